// Round 7
// baseline (361.327 us; speedup 1.0000x reference)
//
#include <hip/hip_runtime.h>
#include <hip/hip_bf16.h>

// SchNet forward on MI355X.
// W(d) -> 4096-bin nearest-neighbor bf16 table; ELL (packed col|bin meta) for
// atomic-free segment sum; barrier-free no-LDS MFMA GEMMs (B streamed from L2
// in fragment layout); fused prep and fused embed+edgeprep dispatches.
// R7: edgeprep fused into embed (both latency-bound, complementary pipes),
//     float4 coords (halves gather transactions); GEMMs drop LDS+barriers
//     (K=128: fragments load straight from global, B L2-resident);
//     k_agg nearest-neighbor table (no lerp: ~13 VALU + 2 loads per edge);
//     ellpad kernel deleted (sentinel via load predicate).

#define NN 50000      // nodes
#define NE 800000     // edges
#define NGR 512       // graphs
#define HD 128        // hidden
#define FD 128        // filters
#define GG 50         // gaussians
#define NB 4096       // table bins (12 bits, nearest-neighbor)
#define DMAXT 12.0f   // table covers [0,12]; beyond, W ~ 0 (gauss < e^-48)
#define ELLS 80       // ELL stride (multiple of 8); deg ~ Poisson(16)
#define SENT 50000u   // sentinel col -> zeroed extra row of t (bin 0)

#define DELTA (10.0f/49.0f)
#define COEFF (-0.5f/(DELTA*DELTA))

#define EMBB 6250     // embed blocks (NN*32/256)
#define EDGB 3125     // edgeprep blocks (NE/256)
#define PW_B 320      // prepw blocks (40960/128)
#define TV_B 100      // tv blocks
#define C4_B 391      // coords-pad blocks (ceil(NN/128))

typedef __attribute__((ext_vector_type(8))) short bf16x8;
typedef __attribute__((ext_vector_type(4))) float f32x4;

static __device__ __forceinline__ float sspf(float x) {
    return fmaxf(x, 0.0f) + log1pf(expf(-fabsf(x))) - 0.69314718055994531f;
}
static __device__ __forceinline__ float asf(unsigned int u) {
    union { unsigned int u; float f; } v; v.u = u; return v.f;
}
static __device__ __forceinline__ unsigned short f2bf(float f) {
    union { float f; unsigned int u; } v; v.f = f;
    unsigned int r = v.u + 0x7FFF + ((v.u >> 16) & 1);   // round-nearest-even
    return (unsigned short)(r >> 16);
}

// Fused prep: [0,NB) table rows -> packed bf16 Tb; [NB,NB+320) weight
// transposes; next 100 blocks tv = emb@w_el; last 391 blocks coords->float4.
__global__ __launch_bounds__(128) void k_prep(const float* __restrict__ w_e1,
                                              const float* __restrict__ b_e1,
                                              const float* __restrict__ w_e2,
                                              const float* __restrict__ b_e2,
                                              const float* __restrict__ w_el,
                                              const float* __restrict__ w_nm,
                                              const float* __restrict__ w_g1,
                                              const float* __restrict__ emb,
                                              const float* __restrict__ coords,
                                              unsigned int* __restrict__ Tb,
                                              unsigned short* __restrict__ welT,
                                              unsigned short* __restrict__ wnmT,
                                              unsigned short* __restrict__ wg1T,
                                              unsigned short* __restrict__ tv,
                                              float4* __restrict__ c4) {
    __shared__ float sbuf[320];
    int bid = blockIdx.x, tx = threadIdx.x;
    if (bid < NB) {
        float* a = sbuf;            // 50
        float* y = sbuf + 64;       // 128
        float* z = sbuf + 192;      // 128
        float d = (float)bid * (DMAXT / (float)(NB - 1));
        if (tx < GG) {
            float o = (float)tx * DELTA;
            float tt = d - o;
            a[tx] = expf(COEFF * tt * tt);
        }
        __syncthreads();
        float acc = b_e1[tx];
        #pragma unroll 10
        for (int g = 0; g < GG; ++g) acc = fmaf(a[g], w_e1[g * FD + tx], acc);
        y[tx] = sspf(acc);
        __syncthreads();
        float acc2 = b_e2[tx];
        #pragma unroll 8
        for (int k = 0; k < FD; ++k) acc2 = fmaf(y[k], w_e2[k * FD + tx], acc2);
        z[tx] = acc2;
        __syncthreads();
        if (tx < 64)
            Tb[bid * 64 + tx] = (unsigned int)f2bf(z[2 * tx])
                              | ((unsigned int)f2bf(z[2 * tx + 1]) << 16);
    } else if (bid < NB + PW_B) {
        int j = (bid - NB) * 128 + tx;          // 0..40959
        if (j < 16384) {                         // welT[n*128+k] = w_el[k*128+n]
            int n = j >> 7, k = j & 127;
            welT[j] = f2bf(w_el[k * 128 + n]);
        } else if (j < 32768) {
            int jj = j - 16384;
            int n = jj >> 7, k = jj & 127;
            wnmT[jj] = f2bf(w_nm[k * 128 + n]);
        } else {
            int jj = j - 32768;
            int n = jj >> 7, k = jj & 127;
            wg1T[jj] = f2bf(w_g1[k * 64 + n]);
        }
    } else if (bid < NB + PW_B + TV_B) {
        int r = bid - (NB + PW_B);
        float* er = sbuf;
        er[tx] = emb[r * HD + tx];
        __syncthreads();
        float acc = 0.f;
        #pragma unroll 8
        for (int k = 0; k < HD; ++k) acc = fmaf(er[k], w_el[k * FD + tx], acc);
        tv[r * FD + tx] = f2bf(acc);
    } else {
        int i = (bid - (NB + PW_B + TV_B)) * 128 + tx;
        if (i < NN)
            c4[i] = make_float4(coords[3 * i], coords[3 * i + 1],
                                coords[3 * i + 2], 0.f);
    }
}

// Fused: blocks [0,EMBB) embed (h fp32 + t bf16 via vocab trick);
// blocks [EMBB, EMBB+EDGB) edgeprep (pack col|bin into ELL slot of row).
__global__ __launch_bounds__(256) void k_embed_edge(const int* __restrict__ charges,
                                                    const float* __restrict__ emb,
                                                    const unsigned short* __restrict__ tv,
                                                    const int* __restrict__ eidx,
                                                    const float4* __restrict__ c4,
                                                    float* __restrict__ h,
                                                    unsigned short* __restrict__ t,
                                                    int* __restrict__ deg,
                                                    unsigned int* __restrict__ emll) {
    int bid = blockIdx.x, tx = threadIdx.x;
    if (bid < EMBB) {
        int idx = bid * 256 + tx;      // exactly NN*32
        int i  = idx >> 5;
        int f4 = idx & 31;
        int c = charges[i];
        ((float4*)h)[idx] = ((const float4*)emb)[c * 32 + f4];
        *(ushort4*)(t + (size_t)i * HD + f4 * 4) =
            *(const ushort4*)(tv + (size_t)c * HD + f4 * 4);
    } else {
        int e = (bid - EMBB) * 256 + tx;   // exactly NE
        int r = eidx[e];
        int c = eidx[NE + e];
        float4 pr = c4[r], pc = c4[c];
        float dx = pr.x - pc.x, dy = pr.y - pc.y, dz = pr.z - pc.z;
        float d = sqrtf(dx * dx + dy * dy + dz * dz);
        float u = d * ((float)(NB - 1) / DMAXT);
        int b = (int)(u + 0.5f);
        if (b > NB - 1) b = NB - 1;
        unsigned int em = (unsigned int)c | ((unsigned int)b << 16);
        int pos = atomicAdd(&deg[r], 1);
        if (pos < ELLS) emll[r * ELLS + pos] = em;
    }
}

// No-LDS MFMA GEMM: C[M,128] = A(bf16) @ BT^T (+Cin)(+bias). 64 rows/block,
// fragments loaded straight from global (B is 32KB, L2-resident). No barriers.
__global__ __launch_bounds__(256, 4) void k_gemm_nolds(const unsigned short* __restrict__ A,
                                                       const unsigned short* __restrict__ BT,
                                                       const float* __restrict__ Cin,
                                                       const float* __restrict__ bias,
                                                       float* __restrict__ Cout,
                                                       unsigned short* __restrict__ Cout16,
                                                       int M) {
    int tx = threadIdx.x;
    int w = tx >> 6, lane = tx & 63, m = lane & 15, quad = lane >> 4;
    int row0 = blockIdx.x * 64;
    int arow = row0 + w * 16 + m;
    if (arow >= M) arow = M - 1;
    const unsigned short* Ap = A + (size_t)arow * 128 + quad * 8;
    const unsigned short* Bp = BT + (size_t)m * 128 + quad * 8;
    f32x4 acc[8];
    #pragma unroll
    for (int ct = 0; ct < 8; ++ct) acc[ct] = (f32x4){0.f, 0.f, 0.f, 0.f};
    #pragma unroll
    for (int s = 0; s < 4; ++s) {
        bf16x8 a = *(const bf16x8*)(Ap + s * 32);
        #pragma unroll
        for (int ct = 0; ct < 8; ++ct) {
            bf16x8 b = *(const bf16x8*)(Bp + ct * 2048 + s * 32);
            acc[ct] = __builtin_amdgcn_mfma_f32_16x16x32_bf16(a, b, acc[ct], 0, 0, 0);
        }
    }
    #pragma unroll
    for (int r = 0; r < 4; ++r) {
        int grow = row0 + w * 16 + quad * 4 + r;
        if (grow >= M) continue;
        #pragma unroll
        for (int ct = 0; ct < 8; ++ct) {
            int col = ct * 16 + m;
            float v = acc[ct][r];
            if (bias) v += bias[col];
            if (Cin)  v += Cin[(size_t)grow * 128 + col];
            if (Cout)   Cout[(size_t)grow * 128 + col] = v;
            if (Cout16) Cout16[(size_t)grow * 128 + col] = f2bf(v);
        }
    }
}

// One wave per node: agg[i,:] = sum_j t[col_j,:] * Tb[bin_j,:]  (nearest bin).
// Per edge: 1 shfl + 4B t-gather + 4B table load + ~13 VALU.
__global__ __launch_bounds__(256) void k_agg(const unsigned short* __restrict__ t,
                                             const unsigned int* __restrict__ Tb,
                                             const int* __restrict__ deg,
                                             const unsigned int* __restrict__ emll,
                                             unsigned short* __restrict__ agg) {
    int wave = (blockIdx.x * blockDim.x + threadIdx.x) >> 6;
    int lane = threadIdx.x & 63;
    if (wave >= NN) return;
    int dg = min(deg[wave], ELLS);
    int dgp = (dg + 7) & ~7;
    const int base = wave * ELLS;
    const unsigned short* tl = t + 2 * lane;
    const unsigned int* Tl = Tb + lane;
    float ax = 0.f, ay = 0.f;
    for (int j0 = 0; j0 < dgp; j0 += 64) {
        int n = min(64, dgp - j0);
        unsigned int myem = SENT;                 // SENT: col=50000 (zero row), bin 0
        if (lane < dg - j0) myem = emll[base + j0 + lane];
        for (int j = 0; j < n; j += 8) {
            #pragma unroll
            for (int u = 0; u < 8; ++u) {
                unsigned int em = (unsigned int)__shfl((int)myem, j + u, 64);
                int c = em & 0xFFFF;
                int b = em >> 16;
                unsigned int tvv = *(const unsigned int*)(tl + (size_t)c * HD);
                unsigned int q = Tl[(size_t)b * 64];
                ax = fmaf(asf(tvv << 16), asf(q << 16), ax);
                ay = fmaf(asf(tvv & 0xFFFF0000u), asf(q & 0xFFFF0000u), ay);
            }
        }
    }
    unsigned int o = (unsigned int)f2bf(ax) | ((unsigned int)f2bf(ay) << 16);
    *(unsigned int*)(agg + (size_t)wave * FD + 2 * lane) = o;
}

// No-LDS readout: p = ssp(h@w_g1+b_g1)@w_g2 + b_g2; atomicAdd(out[batch[row]]).
__global__ __launch_bounds__(256, 4) void k_readout(const unsigned short* __restrict__ hb,
                                                    const int* __restrict__ batch,
                                                    const unsigned short* __restrict__ wg1T,
                                                    const float* __restrict__ b_g1,
                                                    const float* __restrict__ w_g2,
                                                    const float* __restrict__ b_g2,
                                                    float* __restrict__ out) {
    int tx = threadIdx.x;
    int w = tx >> 6, lane = tx & 63, m = lane & 15, quad = lane >> 4;
    int row0 = blockIdx.x * 64;
    int arow = row0 + w * 16 + m;
    if (arow >= NN) arow = NN - 1;
    const unsigned short* Ap = hb + (size_t)arow * 128 + quad * 8;
    const unsigned short* Bp = wg1T + (size_t)m * 128 + quad * 8;
    f32x4 acc[4];
    #pragma unroll
    for (int ct = 0; ct < 4; ++ct) acc[ct] = (f32x4){0.f, 0.f, 0.f, 0.f};
    #pragma unroll
    for (int s = 0; s < 4; ++s) {
        bf16x8 a = *(const bf16x8*)(Ap + s * 32);
        #pragma unroll
        for (int ct = 0; ct < 4; ++ct) {
            bf16x8 b = *(const bf16x8*)(Bp + ct * 2048 + s * 32);
            acc[ct] = __builtin_amdgcn_mfma_f32_16x16x32_bf16(a, b, acc[ct], 0, 0, 0);
        }
    }
    float bg1[4], w2[4];
    #pragma unroll
    for (int ct = 0; ct < 4; ++ct) {
        int col = ct * 16 + m;
        bg1[ct] = b_g1[col];
        w2[ct]  = w_g2[col];
    }
    float bg2 = b_g2[0];
    #pragma unroll
    for (int r = 0; r < 4; ++r) {
        float p = 0.f;
        #pragma unroll
        for (int ct = 0; ct < 4; ++ct) p += sspf(acc[ct][r] + bg1[ct]) * w2[ct];
        p += __shfl_down(p, 8, 16);
        p += __shfl_down(p, 4, 16);
        p += __shfl_down(p, 2, 16);
        p += __shfl_down(p, 1, 16);
        if (m == 0) {
            int row = row0 + w * 16 + quad * 4 + r;
            if (row < NN) atomicAdd(&out[batch[row]], p + bg2);
        }
    }
}

extern "C" void kernel_launch(void* const* d_in, const int* in_sizes, int n_in,
                              void* d_out, int out_size, void* d_ws, size_t ws_size,
                              hipStream_t stream) {
    const int*   charges = (const int*)d_in[0];
    const float* coords  = (const float*)d_in[1];
    const int*   eidx    = (const int*)d_in[2];
    const int*   batch   = (const int*)d_in[3];
    const float* emb     = (const float*)d_in[4];
    const float* w_e1    = (const float*)d_in[5];
    const float* b_e1    = (const float*)d_in[6];
    const float* w_e2    = (const float*)d_in[7];
    const float* b_e2    = (const float*)d_in[8];
    const float* w_el    = (const float*)d_in[9];
    const float* w_nm    = (const float*)d_in[10];
    const float* b_nm    = (const float*)d_in[11];
    const float* w_g1    = (const float*)d_in[12];
    const float* b_g1    = (const float*)d_in[13];
    const float* w_g2    = (const float*)d_in[14];
    const float* b_g2    = (const float*)d_in[15];
    float* out = (float*)d_out;

    char* ws = (char*)d_ws;
    size_t off = 0;
    auto alloc = [&](size_t bytes) -> char* {
        char* p = ws + off;
        off += (bytes + 255) & ~(size_t)255;
        return p;
    };
    float*          h    = (float*)alloc((size_t)NN * HD * 4);               // 25.6 MB
    unsigned short* hb   = (unsigned short*)alloc((size_t)NN * HD * 2);      // 12.8 MB
    unsigned short* t    = (unsigned short*)alloc((size_t)(NN + 1) * HD * 2);// 12.8 MB (+sentinel row)
    unsigned short* aggb = (unsigned short*)alloc((size_t)NN * FD * 2);      // 12.8 MB
    unsigned int*   Tb   = (unsigned int*)alloc((size_t)NB * 64 * 4);        // 1 MB
    int*            deg  = (int*)alloc((size_t)NN * 4);                      // 0.2 MB
    unsigned int*   emll = (unsigned int*)alloc((size_t)NN * ELLS * 4);      // 16 MB
    unsigned short* welT = (unsigned short*)alloc((size_t)HD * FD * 2);
    unsigned short* wnmT = (unsigned short*)alloc((size_t)FD * HD * 2);
    unsigned short* wg1T = (unsigned short*)alloc((size_t)64 * HD * 2);
    unsigned short* tv   = (unsigned short*)alloc((size_t)100 * FD * 2);
    float4*         c4   = (float4*)alloc((size_t)NN * 16);                  // 0.8 MB
    if (off > ws_size) return;  // workspace too small -> fail visibly, no OOB

    hipMemsetAsync(deg, 0, (size_t)NN * 4, stream);
    hipMemsetAsync(out, 0, (size_t)NGR * 4, stream);
    hipMemsetAsync(t + (size_t)NN * HD, 0, HD * 2, stream);   // sentinel row = 0

    k_prep<<<NB + PW_B + TV_B + C4_B, 128, 0, stream>>>(
        w_e1, b_e1, w_e2, b_e2, w_el, w_nm, w_g1, emb, coords,
        Tb, welT, wnmT, wg1T, tv, c4);
    k_embed_edge<<<EMBB + EDGB, 256, 0, stream>>>(charges, emb, tv, eidx, c4,
                                                  h, t, deg, emll);

    // iteration 1 (t came from the vocab trick in k_embed_edge)
    k_agg<<<NN / 4, 256, 0, stream>>>(t, Tb, deg, emll, aggb);
    k_gemm_nolds<<<(NN + 63) / 64, 256, 0, stream>>>(aggb, wnmT, h, b_nm, h, hb, NN);
    // iteration 2
    k_gemm_nolds<<<(NN + 63) / 64, 256, 0, stream>>>(hb, welT, nullptr, nullptr,
                                                     nullptr, t, NN);
    k_agg<<<NN / 4, 256, 0, stream>>>(t, Tb, deg, emll, aggb);
    k_gemm_nolds<<<(NN + 63) / 64, 256, 0, stream>>>(aggb, wnmT, h, b_nm,
                                                     nullptr, hb, NN);

    k_readout<<<(NN + 63) / 64, 256, 0, stream>>>(hb, batch, wg1T, b_g1, w_g2, b_g2, out);
}

// Round 8
// 324.461 us; speedup vs baseline: 1.1136x; 1.1136x over previous
//
#include <hip/hip_runtime.h>
#include <hip/hip_bf16.h>

// SchNet forward on MI355X.
// W(d) -> 4096-bin nearest-neighbor bf16 table; ELL (packed col|bin meta) for
// atomic-free segment sum; LDS-staged bf16 MFMA GEMMs; bf16 residual stream.
// R8: (a) fp32 h removed -> bf16 residual only (saves ~63MB traffic);
//     (b) GEMMs back to LDS-staged (R7's no-LDS fragment streaming was the
//         regression: 36 dependent L2 loads/wave, no overlap), 64-row tiles
//         x 782 blocks for latency hiding; (c) memsets folded into k_prep
//         (11 -> 8 dispatches). edgeprep atomic fabric floor (~50us) accepted.

#define NN 50000      // nodes
#define NE 800000     // edges
#define NGR 512       // graphs
#define HD 128        // hidden
#define FD 128        // filters
#define GG 50         // gaussians
#define NB 4096       // table bins (12 bits, nearest-neighbor)
#define DMAXT 12.0f   // table covers [0,12]; beyond, W ~ 0 (gauss < e^-48)
#define ELLS 80       // ELL stride (multiple of 8); deg ~ Poisson(16)
#define SENT 50000u   // sentinel col -> zeroed extra row of t (bin 0)
#define ASTR 136      // LDS row stride in bf16 elems (128+8): 2-way bank alias = free

#define DELTA (10.0f/49.0f)
#define COEFF (-0.5f/(DELTA*DELTA))

#define EMBB 6250     // embed blocks (NN*32/256)
#define EDGB 3125     // edgeprep blocks (NE/256)
#define PW_B 320      // weight-transpose blocks (40960/128)
#define TV_B 100      // tv blocks
#define C4_B 391      // coords-pad blocks (ceil(NN/128))
#define Z_B  396      // zero blocks (ceil((NN+NGR+64)/128))

typedef __attribute__((ext_vector_type(8))) short bf16x8;
typedef __attribute__((ext_vector_type(4))) float f32x4;

static __device__ __forceinline__ float sspf(float x) {
    return fmaxf(x, 0.0f) + log1pf(expf(-fabsf(x))) - 0.69314718055994531f;
}
static __device__ __forceinline__ float asf(unsigned int u) {
    union { unsigned int u; float f; } v; v.u = u; return v.f;
}
static __device__ __forceinline__ float bf2f(unsigned short b) {
    union { unsigned int u; float f; } v; v.u = ((unsigned int)b) << 16; return v.f;
}
static __device__ __forceinline__ unsigned short f2bf(float f) {
    union { float f; unsigned int u; } v; v.f = f;
    unsigned int r = v.u + 0x7FFF + ((v.u >> 16) & 1);   // round-nearest-even
    return (unsigned short)(r >> 16);
}

// Fused prep: [0,NB) table rows; [NB,+PW_B) weight transposes; [+TV_B) tv =
// emb@w_el; [+C4_B) coords->float4; [+Z_B) zero deg/out/t-sentinel.
__global__ __launch_bounds__(128) void k_prep(const float* __restrict__ w_e1,
                                              const float* __restrict__ b_e1,
                                              const float* __restrict__ w_e2,
                                              const float* __restrict__ b_e2,
                                              const float* __restrict__ w_el,
                                              const float* __restrict__ w_nm,
                                              const float* __restrict__ w_g1,
                                              const float* __restrict__ emb,
                                              const float* __restrict__ coords,
                                              unsigned int* __restrict__ Tb,
                                              unsigned short* __restrict__ welT,
                                              unsigned short* __restrict__ wnmT,
                                              unsigned short* __restrict__ wg1T,
                                              unsigned short* __restrict__ tv,
                                              float4* __restrict__ c4,
                                              int* __restrict__ deg,
                                              float* __restrict__ out,
                                              unsigned int* __restrict__ tsent) {
    __shared__ float sbuf[320];
    int bid = blockIdx.x, tx = threadIdx.x;
    if (bid < NB) {
        float* a = sbuf;            // 50
        float* y = sbuf + 64;       // 128
        float* z = sbuf + 192;      // 128
        float d = (float)bid * (DMAXT / (float)(NB - 1));
        if (tx < GG) {
            float o = (float)tx * DELTA;
            float tt = d - o;
            a[tx] = expf(COEFF * tt * tt);
        }
        __syncthreads();
        float acc = b_e1[tx];
        #pragma unroll 10
        for (int g = 0; g < GG; ++g) acc = fmaf(a[g], w_e1[g * FD + tx], acc);
        y[tx] = sspf(acc);
        __syncthreads();
        float acc2 = b_e2[tx];
        #pragma unroll 8
        for (int k = 0; k < FD; ++k) acc2 = fmaf(y[k], w_e2[k * FD + tx], acc2);
        z[tx] = acc2;
        __syncthreads();
        if (tx < 64)
            Tb[bid * 64 + tx] = (unsigned int)f2bf(z[2 * tx])
                              | ((unsigned int)f2bf(z[2 * tx + 1]) << 16);
    } else if (bid < NB + PW_B) {
        int j = (bid - NB) * 128 + tx;          // 0..40959
        if (j < 16384) {                         // welT[n*128+k] = w_el[k*128+n]
            int n = j >> 7, k = j & 127;
            welT[j] = f2bf(w_el[k * 128 + n]);
        } else if (j < 32768) {
            int jj = j - 16384;
            int n = jj >> 7, k = jj & 127;
            wnmT[jj] = f2bf(w_nm[k * 128 + n]);
        } else {
            int jj = j - 32768;
            int n = jj >> 7, k = jj & 127;
            wg1T[jj] = f2bf(w_g1[k * 64 + n]);
        }
    } else if (bid < NB + PW_B + TV_B) {
        int r = bid - (NB + PW_B);
        float* er = sbuf;
        er[tx] = emb[r * HD + tx];
        __syncthreads();
        float acc = 0.f;
        #pragma unroll 8
        for (int k = 0; k < HD; ++k) acc = fmaf(er[k], w_el[k * FD + tx], acc);
        tv[r * FD + tx] = f2bf(acc);
    } else if (bid < NB + PW_B + TV_B + C4_B) {
        int i = (bid - (NB + PW_B + TV_B)) * 128 + tx;
        if (i < NN)
            c4[i] = make_float4(coords[3 * i], coords[3 * i + 1],
                                coords[3 * i + 2], 0.f);
    } else {
        int j = (bid - (NB + PW_B + TV_B + C4_B)) * 128 + tx;
        if (j < NN) deg[j] = 0;
        else if (j < NN + NGR) out[j - NN] = 0.f;
        else if (j < NN + NGR + 64) tsent[j - NN - NGR] = 0u;
    }
}

// Fused: blocks [0,EMBB) embed (hb bf16 + t bf16 via vocab trick);
// blocks [EMBB, EMBB+EDGB) edgeprep (pack col|bin into ELL slot of row).
__global__ __launch_bounds__(256) void k_embed_edge(const int* __restrict__ charges,
                                                    const float* __restrict__ emb,
                                                    const unsigned short* __restrict__ tv,
                                                    const int* __restrict__ eidx,
                                                    const float4* __restrict__ c4,
                                                    unsigned short* __restrict__ hb,
                                                    unsigned short* __restrict__ t,
                                                    int* __restrict__ deg,
                                                    unsigned int* __restrict__ emll) {
    int bid = blockIdx.x, tx = threadIdx.x;
    if (bid < EMBB) {
        int idx = bid * 256 + tx;      // exactly NN*32
        int i  = idx >> 5;
        int f4 = idx & 31;
        int c = charges[i];
        float4 v = ((const float4*)emb)[c * 32 + f4];
        ushort4 o;
        o.x = f2bf(v.x); o.y = f2bf(v.y); o.z = f2bf(v.z); o.w = f2bf(v.w);
        *(ushort4*)(hb + (size_t)i * HD + f4 * 4) = o;
        *(ushort4*)(t + (size_t)i * HD + f4 * 4) =
            *(const ushort4*)(tv + (size_t)c * HD + f4 * 4);
    } else {
        int e = (bid - EMBB) * 256 + tx;   // exactly NE
        int r = eidx[e];
        int c = eidx[NE + e];
        float4 pr = c4[r], pc = c4[c];
        float dx = pr.x - pc.x, dy = pr.y - pc.y, dz = pr.z - pc.z;
        float d = sqrtf(dx * dx + dy * dy + dz * dz);
        float u = d * ((float)(NB - 1) / DMAXT);
        int b = (int)(u + 0.5f);
        if (b > NB - 1) b = NB - 1;
        unsigned int em = (unsigned int)c | ((unsigned int)b << 16);
        int pos = atomicAdd(&deg[r], 1);
        if (pos < ELLS) emll[r * ELLS + pos] = em;
    }
}

// LDS-staged MFMA GEMM: Out[M,128](bf16) = A[M,128](bf16) @ BT^T (+Cin)(+bias).
// 64-row tiles, 256 thr, 52.2KB LDS -> 3 blocks/CU, grid 782.
__global__ __launch_bounds__(256) void k_gemm(const unsigned short* __restrict__ A,
                                              const unsigned short* __restrict__ BT,
                                              const unsigned short* __restrict__ Cin,
                                              const float* __restrict__ bias,
                                              unsigned short* __restrict__ Out,
                                              int M) {
    __shared__ unsigned short Als[64 * ASTR];    // 17.4 KB
    __shared__ unsigned short Bls[128 * ASTR];   // 34.8 KB
    int tx = threadIdx.x;
    int row0 = blockIdx.x * 64;
    #pragma unroll
    for (int q = 0; q < 4; ++q) {            // A: 64 rows x 16 chunks of 8 bf16
        int l = tx + q * 256;
        int r = l >> 4, c = l & 15;
        int grow = row0 + r;
        uint4 v = make_uint4(0u, 0u, 0u, 0u);
        if (grow < M) v = *(const uint4*)(A + (size_t)grow * 128 + c * 8);
        *(uint4*)(&Als[r * ASTR + c * 8]) = v;
    }
    #pragma unroll
    for (int q = 0; q < 8; ++q) {            // BT: 128 rows x 16 chunks
        int l = tx + q * 256;
        int r = l >> 4, c = l & 15;
        *(uint4*)(&Bls[r * ASTR + c * 8]) = *(const uint4*)(BT + (size_t)r * 128 + c * 8);
    }
    __syncthreads();

    int w = tx >> 6, lane = tx & 63, m = lane & 15, quad = lane >> 4;
    f32x4 acc[8];
    #pragma unroll
    for (int ct = 0; ct < 8; ++ct) acc[ct] = (f32x4){0.f, 0.f, 0.f, 0.f};
    #pragma unroll
    for (int s = 0; s < 4; ++s) {
        bf16x8 a = *(const bf16x8*)(&Als[(w * 16 + m) * ASTR + s * 32 + quad * 8]);
        #pragma unroll
        for (int ct = 0; ct < 8; ++ct) {
            bf16x8 b = *(const bf16x8*)(&Bls[(ct * 16 + m) * ASTR + s * 32 + quad * 8]);
            acc[ct] = __builtin_amdgcn_mfma_f32_16x16x32_bf16(a, b, acc[ct], 0, 0, 0);
        }
    }
    #pragma unroll
    for (int r = 0; r < 4; ++r) {
        int grow = row0 + w * 16 + quad * 4 + r;
        if (grow >= M) continue;
        #pragma unroll
        for (int ct = 0; ct < 8; ++ct) {
            int col = ct * 16 + m;
            float v = acc[ct][r];
            if (bias) v += bias[col];
            if (Cin)  v += bf2f(Cin[(size_t)grow * 128 + col]);
            Out[(size_t)grow * 128 + col] = f2bf(v);
        }
    }
}

// One wave per node: agg[i,:] = sum_j t[col_j,:] * Tb[bin_j,:]  (nearest bin).
// Per edge: 1 shfl + 4B t-gather + 4B table load + ~13 VALU.
__global__ __launch_bounds__(256) void k_agg(const unsigned short* __restrict__ t,
                                             const unsigned int* __restrict__ Tb,
                                             const int* __restrict__ deg,
                                             const unsigned int* __restrict__ emll,
                                             unsigned short* __restrict__ agg) {
    int wave = (blockIdx.x * blockDim.x + threadIdx.x) >> 6;
    int lane = threadIdx.x & 63;
    if (wave >= NN) return;
    int dg = min(deg[wave], ELLS);
    int dgp = (dg + 7) & ~7;
    const int base = wave * ELLS;
    const unsigned short* tl = t + 2 * lane;
    const unsigned int* Tl = Tb + lane;
    float ax = 0.f, ay = 0.f;
    for (int j0 = 0; j0 < dgp; j0 += 64) {
        int n = min(64, dgp - j0);
        unsigned int myem = SENT;                 // SENT: col=50000 (zero row), bin 0
        if (lane < dg - j0) myem = emll[base + j0 + lane];
        for (int j = 0; j < n; j += 8) {
            #pragma unroll
            for (int u = 0; u < 8; ++u) {
                unsigned int em = (unsigned int)__shfl((int)myem, j + u, 64);
                int c = em & 0xFFFF;
                int b = em >> 16;
                unsigned int tvv = *(const unsigned int*)(tl + (size_t)c * HD);
                unsigned int q = Tl[(size_t)b * 64];
                ax = fmaf(asf(tvv << 16), asf(q << 16), ax);
                ay = fmaf(asf(tvv & 0xFFFF0000u), asf(q & 0xFFFF0000u), ay);
            }
        }
    }
    unsigned int o = (unsigned int)f2bf(ax) | ((unsigned int)f2bf(ay) << 16);
    *(unsigned int*)(agg + (size_t)wave * FD + 2 * lane) = o;
}

// LDS-staged readout: p = ssp(h@w_g1+b_g1)@w_g2 + b_g2; atomicAdd per row.
__global__ __launch_bounds__(256) void k_readout(const unsigned short* __restrict__ hb,
                                                 const int* __restrict__ batch,
                                                 const unsigned short* __restrict__ wg1T,
                                                 const float* __restrict__ b_g1,
                                                 const float* __restrict__ w_g2,
                                                 const float* __restrict__ b_g2,
                                                 float* __restrict__ out) {
    __shared__ unsigned short Als[64 * ASTR];    // 17.4 KB
    __shared__ unsigned short Bls[64 * ASTR];    // 17.4 KB
    int tx = threadIdx.x;
    int row0 = blockIdx.x * 64;
    #pragma unroll
    for (int q = 0; q < 4; ++q) {
        int l = tx + q * 256;
        int r = l >> 4, c = l & 15;
        int grow = row0 + r;
        uint4 v = make_uint4(0u, 0u, 0u, 0u);
        if (grow < NN) v = *(const uint4*)(hb + (size_t)grow * 128 + c * 8);
        *(uint4*)(&Als[r * ASTR + c * 8]) = v;
    }
    #pragma unroll
    for (int q = 0; q < 4; ++q) {
        int l = tx + q * 256;                // 64 rows x 16 chunks = 1024
        int r = l >> 4, c = l & 15;
        *(uint4*)(&Bls[r * ASTR + c * 8]) = *(const uint4*)(wg1T + (size_t)r * 128 + c * 8);
    }
    __syncthreads();

    int w = tx >> 6, lane = tx & 63, m = lane & 15, quad = lane >> 4;
    f32x4 acc[4];
    #pragma unroll
    for (int ct = 0; ct < 4; ++ct) acc[ct] = (f32x4){0.f, 0.f, 0.f, 0.f};
    #pragma unroll
    for (int s = 0; s < 4; ++s) {
        bf16x8 a = *(const bf16x8*)(&Als[(w * 16 + m) * ASTR + s * 32 + quad * 8]);
        #pragma unroll
        for (int ct = 0; ct < 4; ++ct) {
            bf16x8 b = *(const bf16x8*)(&Bls[(ct * 16 + m) * ASTR + s * 32 + quad * 8]);
            acc[ct] = __builtin_amdgcn_mfma_f32_16x16x32_bf16(a, b, acc[ct], 0, 0, 0);
        }
    }
    float bg1[4], w2[4];
    #pragma unroll
    for (int ct = 0; ct < 4; ++ct) {
        int col = ct * 16 + m;
        bg1[ct] = b_g1[col];
        w2[ct]  = w_g2[col];
    }
    float bg2 = b_g2[0];
    #pragma unroll
    for (int r = 0; r < 4; ++r) {
        float p = 0.f;
        #pragma unroll
        for (int ct = 0; ct < 4; ++ct) p += sspf(acc[ct][r] + bg1[ct]) * w2[ct];
        p += __shfl_down(p, 8, 16);
        p += __shfl_down(p, 4, 16);
        p += __shfl_down(p, 2, 16);
        p += __shfl_down(p, 1, 16);
        if (m == 0) {
            int row = row0 + w * 16 + quad * 4 + r;
            if (row < NN) atomicAdd(&out[batch[row]], p + bg2);
        }
    }
}

extern "C" void kernel_launch(void* const* d_in, const int* in_sizes, int n_in,
                              void* d_out, int out_size, void* d_ws, size_t ws_size,
                              hipStream_t stream) {
    const int*   charges = (const int*)d_in[0];
    const float* coords  = (const float*)d_in[1];
    const int*   eidx    = (const int*)d_in[2];
    const int*   batch   = (const int*)d_in[3];
    const float* emb     = (const float*)d_in[4];
    const float* w_e1    = (const float*)d_in[5];
    const float* b_e1    = (const float*)d_in[6];
    const float* w_e2    = (const float*)d_in[7];
    const float* b_e2    = (const float*)d_in[8];
    const float* w_el    = (const float*)d_in[9];
    const float* w_nm    = (const float*)d_in[10];
    const float* b_nm    = (const float*)d_in[11];
    const float* w_g1    = (const float*)d_in[12];
    const float* b_g1    = (const float*)d_in[13];
    const float* w_g2    = (const float*)d_in[14];
    const float* b_g2    = (const float*)d_in[15];
    float* out = (float*)d_out;

    char* ws = (char*)d_ws;
    size_t off = 0;
    auto alloc = [&](size_t bytes) -> char* {
        char* p = ws + off;
        off += (bytes + 255) & ~(size_t)255;
        return p;
    };
    unsigned short* hb   = (unsigned short*)alloc((size_t)NN * HD * 2);      // 12.8 MB
    unsigned short* t    = (unsigned short*)alloc((size_t)(NN + 1) * HD * 2);// 12.8 MB (+sentinel row)
    unsigned short* aggb = (unsigned short*)alloc((size_t)NN * FD * 2);      // 12.8 MB
    unsigned int*   Tb   = (unsigned int*)alloc((size_t)NB * 64 * 4);        // 1 MB
    int*            deg  = (int*)alloc((size_t)NN * 4);                      // 0.2 MB
    unsigned int*   emll = (unsigned int*)alloc((size_t)NN * ELLS * 4);      // 16 MB
    unsigned short* welT = (unsigned short*)alloc((size_t)HD * FD * 2);
    unsigned short* wnmT = (unsigned short*)alloc((size_t)FD * HD * 2);
    unsigned short* wg1T = (unsigned short*)alloc((size_t)64 * HD * 2);
    unsigned short* tv   = (unsigned short*)alloc((size_t)100 * FD * 2);
    float4*         c4   = (float4*)alloc((size_t)NN * 16);                  // 0.8 MB
    if (off > ws_size) return;  // workspace too small -> fail visibly, no OOB

    k_prep<<<NB + PW_B + TV_B + C4_B + Z_B, 128, 0, stream>>>(
        w_e1, b_e1, w_e2, b_e2, w_el, w_nm, w_g1, emb, coords,
        Tb, welT, wnmT, wg1T, tv, c4,
        deg, out, (unsigned int*)(t + (size_t)NN * HD));
    k_embed_edge<<<EMBB + EDGB, 256, 0, stream>>>(charges, emb, tv, eidx, c4,
                                                  hb, t, deg, emll);

    // iteration 1 (t came from the vocab trick in k_embed_edge)
    k_agg<<<NN / 4, 256, 0, stream>>>(t, Tb, deg, emll, aggb);
    k_gemm<<<(NN + 63) / 64, 256, 0, stream>>>(aggb, wnmT, hb, b_nm, hb, NN);
    // iteration 2
    k_gemm<<<(NN + 63) / 64, 256, 0, stream>>>(hb, welT, nullptr, nullptr, t, NN);
    k_agg<<<NN / 4, 256, 0, stream>>>(t, Tb, deg, emll, aggb);
    k_gemm<<<(NN + 63) / 64, 256, 0, stream>>>(aggb, wnmT, hb, b_nm, hb, NN);

    k_readout<<<(NN + 63) / 64, 256, 0, stream>>>(hb, batch, wg1T, b_g1, w_g2, b_g2, out);
}

// Round 9
// 284.597 us; speedup vs baseline: 1.2696x; 1.1401x over previous
//
#include <hip/hip_runtime.h>
#include <hip/hip_bf16.h>

// SchNet forward on MI355X.
// W(d) -> 4096-bin nearest-neighbor bf16 table; ELL (packed col|bin) for
// atomic-free segment sum; bf16 MFMA; bf16 data plane.
// R9: residual stream is LINEAR -> telescope the GEMM chain with composed
//     weights: t2 = t1 + agg1@(w_nm@w_el) + b_nm@w_el;
//     h2@w_g1 = (emb@w_g1)[charge] + (agg1+agg2)@(w_nm@w_g1) + 2 b_nm@w_g1.
//     h is never materialized; 3 GEMMs -> 1; agg2 emits asum directly.
//     Pipeline: prep -> embed+edgeprep -> agg1 -> gemm(t2) -> agg2 -> readout.

#define NN 50000      // nodes
#define NE 800000     // edges
#define NGR 512       // graphs
#define HD 128        // hidden
#define FD 128        // filters
#define GG 50         // gaussians
#define NB 4096       // table bins (nearest-neighbor)
#define DMAXT 12.0f   // table covers [0,12]; beyond, W ~ const (gauss < e^-48)
#define ELLS 80       // ELL stride (multiple of 8); deg ~ Poisson(16)
#define SENT 50000u   // sentinel col -> zeroed extra row of t (bin 0)
#define ASTR 136      // LDS row stride in bf16 elems (128+8): 2-way alias free

#define DELTA (10.0f/49.0f)
#define COEFF (-0.5f/(DELTA*DELTA))

// k_prep grid segments
#define TB_B 4096     // table rows
#define WF_B 128      // w_fT cols
#define WH_B 64       // w_hT cols
#define TV_B 100      // tv rows
#define HG_B 100      // hg rows
#define BV_B 2        // bv + gvec
#define C4_B 391      // coords pad
#define Z_B  396      // zero deg/out/sentinels
// k_embed_edge grid segments
#define EMBB 3125     // t1 gather: NN*16 uint4 / 256
#define EDGB 3125     // NE/256

typedef __attribute__((ext_vector_type(8))) short bf16x8;
typedef __attribute__((ext_vector_type(4))) float f32x4;

static __device__ __forceinline__ float sspf(float x) {
    return fmaxf(x, 0.0f) + log1pf(expf(-fabsf(x))) - 0.69314718055994531f;
}
static __device__ __forceinline__ float asf(unsigned int u) {
    union { unsigned int u; float f; } v; v.u = u; return v.f;
}
static __device__ __forceinline__ float bf2f(unsigned short b) {
    union { unsigned int u; float f; } v; v.u = ((unsigned int)b) << 16; return v.f;
}
static __device__ __forceinline__ unsigned short f2bf(float f) {
    union { float f; unsigned int u; } v; v.f = f;
    unsigned int r = v.u + 0x7FFF + ((v.u >> 16) & 1);   // round-nearest-even
    return (unsigned short)(r >> 16);
}

// Fused prep. Segments (by blockIdx.x):
//  [0,TB_B): Tb table; +WF_B: w_fT[n][k]=(w_nm@w_el)[k][n]; +WH_B: w_hT;
//  +TV_B: tv=emb@w_el; +HG_B: hg=emb@w_g1; +BV_B: bv=b_nm@w_el,
//  gvec=b_g1+2*b_nm@w_g1; +C4_B: coords->float4; +Z_B: zero deg/out/sentinels.
__global__ __launch_bounds__(128) void k_prep(const float* __restrict__ w_e1,
                                              const float* __restrict__ b_e1,
                                              const float* __restrict__ w_e2,
                                              const float* __restrict__ b_e2,
                                              const float* __restrict__ w_el,
                                              const float* __restrict__ w_nm,
                                              const float* __restrict__ b_nm,
                                              const float* __restrict__ w_g1,
                                              const float* __restrict__ b_g1,
                                              const float* __restrict__ emb,
                                              const float* __restrict__ coords,
                                              unsigned int* __restrict__ Tb,
                                              unsigned short* __restrict__ wfT,
                                              unsigned short* __restrict__ whT,
                                              unsigned short* __restrict__ tv,
                                              unsigned short* __restrict__ hg,
                                              float* __restrict__ bv,
                                              float* __restrict__ gvec,
                                              float4* __restrict__ c4,
                                              int* __restrict__ deg,
                                              float* __restrict__ out,
                                              unsigned int* __restrict__ t1s,
                                              unsigned int* __restrict__ t2s) {
    __shared__ float sbuf[320];
    int bid = blockIdx.x, tx = threadIdx.x;
    if (bid < TB_B) {
        float* a = sbuf;            // 50
        float* y = sbuf + 64;       // 128
        float* z = sbuf + 192;      // 128
        float d = (float)bid * (DMAXT / (float)(NB - 1));
        if (tx < GG) {
            float o = (float)tx * DELTA;
            float tt = d - o;
            a[tx] = expf(COEFF * tt * tt);
        }
        __syncthreads();
        float acc = b_e1[tx];
        #pragma unroll 10
        for (int g = 0; g < GG; ++g) acc = fmaf(a[g], w_e1[g * FD + tx], acc);
        y[tx] = sspf(acc);
        __syncthreads();
        float acc2 = b_e2[tx];
        #pragma unroll 8
        for (int k = 0; k < FD; ++k) acc2 = fmaf(y[k], w_e2[k * FD + tx], acc2);
        z[tx] = acc2;
        __syncthreads();
        if (tx < 64)
            Tb[bid * 64 + tx] = (unsigned int)f2bf(z[2 * tx])
                              | ((unsigned int)f2bf(z[2 * tx + 1]) << 16);
    } else if (bid < TB_B + WF_B) {
        int n = bid - TB_B;                       // output col of w_f
        sbuf[tx] = w_el[tx * 128 + n];            // w_el column n
        __syncthreads();
        float acc = 0.f;
        #pragma unroll 8
        for (int j = 0; j < 128; ++j) acc = fmaf(w_nm[tx * 128 + j], sbuf[j], acc);
        wfT[n * 128 + tx] = f2bf(acc);            // wfT[n][k=tx]
    } else if (bid < TB_B + WF_B + WH_B) {
        int n = bid - TB_B - WF_B;                // output col of w_h (0..63)
        sbuf[tx] = w_g1[tx * 64 + n];             // w_g1 column n
        __syncthreads();
        float acc = 0.f;
        #pragma unroll 8
        for (int j = 0; j < 128; ++j) acc = fmaf(w_nm[tx * 128 + j], sbuf[j], acc);
        whT[n * 128 + tx] = f2bf(acc);            // whT[n][k=tx]
    } else if (bid < TB_B + WF_B + WH_B + TV_B) {
        int r = bid - TB_B - WF_B - WH_B;
        sbuf[tx] = emb[r * HD + tx];
        __syncthreads();
        float acc = 0.f;
        #pragma unroll 8
        for (int k = 0; k < HD; ++k) acc = fmaf(sbuf[k], w_el[k * FD + tx], acc);
        tv[r * FD + tx] = f2bf(acc);
    } else if (bid < TB_B + WF_B + WH_B + TV_B + HG_B) {
        int c = bid - TB_B - WF_B - WH_B - TV_B;
        sbuf[tx] = emb[c * HD + tx];
        __syncthreads();
        if (tx < 64) {
            float acc = 0.f;
            #pragma unroll 8
            for (int k = 0; k < HD; ++k) acc = fmaf(sbuf[k], w_g1[k * 64 + tx], acc);
            hg[c * 64 + tx] = f2bf(acc);
        }
    } else if (bid < TB_B + WF_B + WH_B + TV_B + HG_B + BV_B) {
        int which = bid - (TB_B + WF_B + WH_B + TV_B + HG_B);
        if (which == 0) {
            float acc = 0.f;
            for (int k = 0; k < HD; ++k) acc = fmaf(b_nm[k], w_el[k * FD + tx], acc);
            bv[tx] = acc;                          // b_nm @ w_el
        } else if (tx < 64) {
            float acc = 0.f;
            for (int k = 0; k < HD; ++k) acc = fmaf(b_nm[k], w_g1[k * 64 + tx], acc);
            gvec[tx] = b_g1[tx] + 2.0f * acc;      // readout G1 bias
        }
    } else if (bid < TB_B + WF_B + WH_B + TV_B + HG_B + BV_B + C4_B) {
        int i = (bid - (TB_B + WF_B + WH_B + TV_B + HG_B + BV_B)) * 128 + tx;
        if (i < NN)
            c4[i] = make_float4(coords[3 * i], coords[3 * i + 1],
                                coords[3 * i + 2], 0.f);
    } else {
        int j = (bid - (TB_B + WF_B + WH_B + TV_B + HG_B + BV_B + C4_B)) * 128 + tx;
        if (j < NN) deg[j] = 0;
        else if (j < NN + NGR) out[j - NN] = 0.f;
        else if (j < NN + NGR + 64) t1s[j - NN - NGR] = 0u;
        else if (j < NN + NGR + 128) t2s[j - NN - NGR - 64] = 0u;
    }
}

// Fused: [0,EMBB): t1[i] = tv[charges[i]] (uint4 per thread);
// [EMBB,+EDGB): edgeprep (pack col|bin into ELL slot of row).
__global__ __launch_bounds__(256) void k_embed_edge(const int* __restrict__ charges,
                                                    const unsigned short* __restrict__ tv,
                                                    const int* __restrict__ eidx,
                                                    const float4* __restrict__ c4,
                                                    unsigned short* __restrict__ t1,
                                                    int* __restrict__ deg,
                                                    unsigned int* __restrict__ emll) {
    int bid = blockIdx.x, tx = threadIdx.x;
    if (bid < EMBB) {
        int idx = bid * 256 + tx;      // exactly NN*16 uint4s
        int i = idx >> 4;
        int f = idx & 15;
        int c = charges[i];
        ((uint4*)t1)[(size_t)i * 16 + f] = ((const uint4*)tv)[(size_t)c * 16 + f];
    } else {
        int e = (bid - EMBB) * 256 + tx;   // exactly NE
        int r = eidx[e];
        int c = eidx[NE + e];
        float4 pr = c4[r], pc = c4[c];
        float dx = pr.x - pc.x, dy = pr.y - pc.y, dz = pr.z - pc.z;
        float d = sqrtf(dx * dx + dy * dy + dz * dz);
        float u = d * ((float)(NB - 1) / DMAXT);
        int b = (int)(u + 0.5f);
        if (b > NB - 1) b = NB - 1;
        unsigned int em = (unsigned int)c | ((unsigned int)b << 16);
        int pos = atomicAdd(&deg[r], 1);
        if (pos < ELLS) emll[r * ELLS + pos] = em;
    }
}

// LDS-staged MFMA GEMM: Out[M,128](bf16) = A(bf16) @ BT^T (+Cin bf16)(+bias f32).
__global__ __launch_bounds__(256) void k_gemm(const unsigned short* __restrict__ A,
                                              const unsigned short* __restrict__ BT,
                                              const unsigned short* __restrict__ Cin,
                                              const float* __restrict__ bias,
                                              unsigned short* __restrict__ Out,
                                              int M) {
    __shared__ unsigned short Als[64 * ASTR];    // 17.4 KB
    __shared__ unsigned short Bls[128 * ASTR];   // 34.8 KB
    int tx = threadIdx.x;
    int row0 = blockIdx.x * 64;
    #pragma unroll
    for (int q = 0; q < 4; ++q) {            // A: 64 rows x 16 chunks of 8 bf16
        int l = tx + q * 256;
        int r = l >> 4, c = l & 15;
        int grow = row0 + r;
        uint4 v = make_uint4(0u, 0u, 0u, 0u);
        if (grow < M) v = *(const uint4*)(A + (size_t)grow * 128 + c * 8);
        *(uint4*)(&Als[r * ASTR + c * 8]) = v;
    }
    #pragma unroll
    for (int q = 0; q < 8; ++q) {            // BT: 128 rows x 16 chunks
        int l = tx + q * 256;
        int r = l >> 4, c = l & 15;
        *(uint4*)(&Bls[r * ASTR + c * 8]) = *(const uint4*)(BT + (size_t)r * 128 + c * 8);
    }
    __syncthreads();

    int w = tx >> 6, lane = tx & 63, m = lane & 15, quad = lane >> 4;
    f32x4 acc[8];
    #pragma unroll
    for (int ct = 0; ct < 8; ++ct) acc[ct] = (f32x4){0.f, 0.f, 0.f, 0.f};
    #pragma unroll
    for (int s = 0; s < 4; ++s) {
        bf16x8 a = *(const bf16x8*)(&Als[(w * 16 + m) * ASTR + s * 32 + quad * 8]);
        #pragma unroll
        for (int ct = 0; ct < 8; ++ct) {
            bf16x8 b = *(const bf16x8*)(&Bls[(ct * 16 + m) * ASTR + s * 32 + quad * 8]);
            acc[ct] = __builtin_amdgcn_mfma_f32_16x16x32_bf16(a, b, acc[ct], 0, 0, 0);
        }
    }
    #pragma unroll
    for (int r = 0; r < 4; ++r) {
        int grow = row0 + w * 16 + quad * 4 + r;
        if (grow >= M) continue;
        #pragma unroll
        for (int ct = 0; ct < 8; ++ct) {
            int col = ct * 16 + m;
            float v = acc[ct][r];
            if (bias) v += bias[col];
            if (Cin)  v += bf2f(Cin[(size_t)grow * 128 + col]);
            Out[(size_t)grow * 128 + col] = f2bf(v);
        }
    }
}

// One wave per node: out[i,:] = sum_j t[col_j,:] * Tb[bin_j,:] (+ addin[i,:]).
__global__ __launch_bounds__(256) void k_agg(const unsigned short* __restrict__ t,
                                             const unsigned int* __restrict__ Tb,
                                             const int* __restrict__ deg,
                                             const unsigned int* __restrict__ emll,
                                             const unsigned short* __restrict__ addin,
                                             unsigned short* __restrict__ outb) {
    int wave = (blockIdx.x * blockDim.x + threadIdx.x) >> 6;
    int lane = threadIdx.x & 63;
    if (wave >= NN) return;
    int dg = min(deg[wave], ELLS);
    int dgp = (dg + 7) & ~7;
    const int base = wave * ELLS;
    const unsigned short* tl = t + 2 * lane;
    const unsigned int* Tl = Tb + lane;
    float ax = 0.f, ay = 0.f;
    for (int j0 = 0; j0 < dgp; j0 += 64) {
        int n = min(64, dgp - j0);
        unsigned int myem = SENT;                 // SENT: col=50000 (zero row), bin 0
        if (lane < dg - j0) myem = emll[base + j0 + lane];
        for (int j = 0; j < n; j += 8) {
            #pragma unroll
            for (int u = 0; u < 8; ++u) {
                unsigned int em = (unsigned int)__shfl((int)myem, j + u, 64);
                int c = em & 0xFFFF;
                int b = em >> 16;
                unsigned int tvv = *(const unsigned int*)(tl + (size_t)c * HD);
                unsigned int q = Tl[(size_t)b * 64];
                ax = fmaf(asf(tvv << 16), asf(q << 16), ax);
                ay = fmaf(asf(tvv & 0xFFFF0000u), asf(q & 0xFFFF0000u), ay);
            }
        }
    }
    if (addin) {
        unsigned int av = *(const unsigned int*)(addin + (size_t)wave * FD + 2 * lane);
        ax += asf(av << 16);
        ay += asf(av & 0xFFFF0000u);
    }
    unsigned int o = (unsigned int)f2bf(ax) | ((unsigned int)f2bf(ay) << 16);
    *(unsigned int*)(outb + (size_t)wave * FD + 2 * lane) = o;
}

// Readout: G1 = asum@w_h + hg[charge[row]] + gvec; p = ssp(G1)@w_g2 + b_g2;
// atomicAdd(out[batch[row]], p). ~35KB LDS -> 4 blocks/CU.
__global__ __launch_bounds__(256) void k_readout(const unsigned short* __restrict__ asum,
                                                 const int* __restrict__ charges,
                                                 const int* __restrict__ batch,
                                                 const unsigned short* __restrict__ whT,
                                                 const unsigned short* __restrict__ hg,
                                                 const float* __restrict__ gvec,
                                                 const float* __restrict__ w_g2,
                                                 const float* __restrict__ b_g2,
                                                 float* __restrict__ out) {
    __shared__ unsigned short Als[64 * ASTR];    // asum tile
    __shared__ unsigned short Bls[64 * ASTR];    // whT (64 cols x 128 k)
    int tx = threadIdx.x;
    int row0 = blockIdx.x * 64;
    #pragma unroll
    for (int q = 0; q < 4; ++q) {
        int l = tx + q * 256;
        int r = l >> 4, c = l & 15;
        int grow = row0 + r;
        uint4 v = make_uint4(0u, 0u, 0u, 0u);
        if (grow < NN) v = *(const uint4*)(asum + (size_t)grow * 128 + c * 8);
        *(uint4*)(&Als[r * ASTR + c * 8]) = v;
    }
    #pragma unroll
    for (int q = 0; q < 4; ++q) {
        int l = tx + q * 256;                // 64 rows x 16 chunks
        int r = l >> 4, c = l & 15;
        *(uint4*)(&Bls[r * ASTR + c * 8]) = *(const uint4*)(whT + (size_t)r * 128 + c * 8);
    }
    __syncthreads();

    int w = tx >> 6, lane = tx & 63, m = lane & 15, quad = lane >> 4;
    f32x4 acc[4];
    #pragma unroll
    for (int ct = 0; ct < 4; ++ct) acc[ct] = (f32x4){0.f, 0.f, 0.f, 0.f};
    #pragma unroll
    for (int s = 0; s < 4; ++s) {
        bf16x8 a = *(const bf16x8*)(&Als[(w * 16 + m) * ASTR + s * 32 + quad * 8]);
        #pragma unroll
        for (int ct = 0; ct < 4; ++ct) {
            bf16x8 b = *(const bf16x8*)(&Bls[(ct * 16 + m) * ASTR + s * 32 + quad * 8]);
            acc[ct] = __builtin_amdgcn_mfma_f32_16x16x32_bf16(a, b, acc[ct], 0, 0, 0);
        }
    }
    float gv[4], w2[4];
    #pragma unroll
    for (int ct = 0; ct < 4; ++ct) {
        int col = ct * 16 + m;
        gv[ct] = gvec[col];
        w2[ct] = w_g2[col];
    }
    float bg2 = b_g2[0];
    #pragma unroll
    for (int r = 0; r < 4; ++r) {
        int row = row0 + w * 16 + quad * 4 + r;
        int rowc = row < NN ? row : NN - 1;
        int ch = charges[rowc];
        float p = 0.f;
        #pragma unroll
        for (int ct = 0; ct < 4; ++ct) {
            int col = ct * 16 + m;
            float g1 = acc[ct][r] + bf2f(hg[ch * 64 + col]) + gv[ct];
            p += sspf(g1) * w2[ct];
        }
        p += __shfl_down(p, 8, 16);
        p += __shfl_down(p, 4, 16);
        p += __shfl_down(p, 2, 16);
        p += __shfl_down(p, 1, 16);
        if (m == 0 && row < NN) atomicAdd(&out[batch[row]], p + bg2);
    }
}

extern "C" void kernel_launch(void* const* d_in, const int* in_sizes, int n_in,
                              void* d_out, int out_size, void* d_ws, size_t ws_size,
                              hipStream_t stream) {
    const int*   charges = (const int*)d_in[0];
    const float* coords  = (const float*)d_in[1];
    const int*   eidx    = (const int*)d_in[2];
    const int*   batch   = (const int*)d_in[3];
    const float* emb     = (const float*)d_in[4];
    const float* w_e1    = (const float*)d_in[5];
    const float* b_e1    = (const float*)d_in[6];
    const float* w_e2    = (const float*)d_in[7];
    const float* b_e2    = (const float*)d_in[8];
    const float* w_el    = (const float*)d_in[9];
    const float* w_nm    = (const float*)d_in[10];
    const float* b_nm    = (const float*)d_in[11];
    const float* w_g1    = (const float*)d_in[12];
    const float* b_g1    = (const float*)d_in[13];
    const float* w_g2    = (const float*)d_in[14];
    const float* b_g2    = (const float*)d_in[15];
    float* out = (float*)d_out;

    char* ws = (char*)d_ws;
    size_t off = 0;
    auto alloc = [&](size_t bytes) -> char* {
        char* p = ws + off;
        off += (bytes + 255) & ~(size_t)255;
        return p;
    };
    unsigned short* t1   = (unsigned short*)alloc((size_t)(NN + 1) * HD * 2); // +sentinel
    unsigned short* t2   = (unsigned short*)alloc((size_t)(NN + 1) * HD * 2); // +sentinel
    unsigned short* agg1 = (unsigned short*)alloc((size_t)NN * FD * 2);
    unsigned short* asum = (unsigned short*)alloc((size_t)NN * FD * 2);
    unsigned int*   Tb   = (unsigned int*)alloc((size_t)NB * 64 * 4);         // 1 MB
    int*            deg  = (int*)alloc((size_t)NN * 4);
    unsigned int*   emll = (unsigned int*)alloc((size_t)NN * ELLS * 4);       // 16 MB
    unsigned short* wfT  = (unsigned short*)alloc((size_t)128 * 128 * 2);
    unsigned short* whT  = (unsigned short*)alloc((size_t)64 * 128 * 2);
    unsigned short* tv   = (unsigned short*)alloc((size_t)100 * 128 * 2);
    unsigned short* hg   = (unsigned short*)alloc((size_t)100 * 64 * 2);
    float*          bv   = (float*)alloc(128 * 4);
    float*          gvec = (float*)alloc(64 * 4);
    float4*         c4   = (float4*)alloc((size_t)NN * 16);
    if (off > ws_size) return;  // workspace too small -> fail visibly, no OOB

    k_prep<<<TB_B + WF_B + WH_B + TV_B + HG_B + BV_B + C4_B + Z_B, 128, 0, stream>>>(
        w_e1, b_e1, w_e2, b_e2, w_el, w_nm, b_nm, w_g1, b_g1, emb, coords,
        Tb, wfT, whT, tv, hg, bv, gvec, c4, deg, out,
        (unsigned int*)(t1 + (size_t)NN * HD), (unsigned int*)(t2 + (size_t)NN * HD));
    k_embed_edge<<<EMBB + EDGB, 256, 0, stream>>>(charges, tv, eidx, c4,
                                                  t1, deg, emll);

    k_agg<<<NN / 4, 256, 0, stream>>>(t1, Tb, deg, emll, nullptr, agg1);
    // t2 = t1 + agg1 @ w_f + b_nm@w_el
    k_gemm<<<(NN + 63) / 64, 256, 0, stream>>>(agg1, wfT, t1, bv, t2, NN);
    // asum = agg1 + AGG(t2)
    k_agg<<<NN / 4, 256, 0, stream>>>(t2, Tb, deg, emll, agg1, asum);

    k_readout<<<(NN + 63) / 64, 256, 0, stream>>>(asum, charges, batch, whT, hg,
                                                  gvec, w_g2, b_g2, out);
}